// Round 1
// baseline (158.965 us; speedup 1.0000x reference)
//
#include <hip/hip_runtime.h>

// SnakeBrain fused kernel: 2x GCNConv(chain stencil) + mean-pool + MLP head.
// One block of 256 threads per snake (graph); thread i = node i of the chain.
// B=4096, L=256, HID=32, FIN=64. All fp32 (no fp32 MFMA on CDNA4 -> VALU).

#define NB  4096
#define CL  256
#define HID 32
#define FIN 64

__global__ __launch_bounds__(256) void snake_fused(
    const float* __restrict__ x,
    const float* __restrict__ heads,
    const float* __restrict__ body_sizes,
    const float* __restrict__ fruits,
    const float* __restrict__ W1, const float* __restrict__ b1,
    const float* __restrict__ W2, const float* __restrict__ b2,
    const float* __restrict__ Wr, const float* __restrict__ br,
    const float* __restrict__ Wa1, const float* __restrict__ ba1,
    const float* __restrict__ Wa2, const float* __restrict__ ba2,
    const float* __restrict__ Wc, const float* __restrict__ bc,
    const float* __restrict__ Wp, const float* __restrict__ bp,
    const float* __restrict__ Wv, const float* __restrict__ bv,
    float* __restrict__ out)
{
    // +1 pad: stencil/pool accesses stride 33 == 1 (mod 32) -> conflict-free
    __shared__ float hbuf[CL][HID + 1];
    __shared__ float pooled[HID];
    __shared__ float partial[8][HID];   // pooling partials; reused as aux1 buffer
    __shared__ float catbuf[FIN];       // [body_emb | aux2]
    __shared__ float cmb[FIN];

    const int b = blockIdx.x;
    const int i = threadIdx.x;
    const int n = b * CL + i;

    // GCN norm coefficients: deg = 3 interior, 2 at chain ends (incl. self-loop)
    const float INV_S3 = 0.57735026918962576f;  // 1/sqrt(3)
    const float INV_S2 = 0.70710678118654752f;  // 1/sqrt(2)
    const float di   = (i == 0 || i == CL - 1) ? INV_S2 : INV_S3;
    const float dil  = (i == 1)      ? INV_S2 : INV_S3;   // dinv of node i-1
    const float dirr = (i == CL - 2) ? INV_S2 : INV_S3;   // dinv of node i+1
    const float nc = di * di;
    const float nl = (i > 0)      ? di * dil  : 0.0f;
    const float nr = (i < CL - 1) ? di * dirr : 0.0f;
    const int il = (i > 0)      ? i - 1 : i;  // safe dummy when nl==0
    const int ir = (i < CL - 1) ? i + 1 : i;  // safe dummy when nr==0

    // ---- layer 1: t1 = x @ W1 (2 -> 32) into LDS ----
    const float2 xv = reinterpret_cast<const float2*>(x)[n];
    #pragma unroll
    for (int c = 0; c < HID; ++c)
        hbuf[i][c] = fmaf(xv.x, W1[c], xv.y * W1[HID + c]);
    __syncthreads();

    // ---- stencil 1 + bias + relu -> r1 (registers) ----
    float r1[HID];
    #pragma unroll
    for (int c = 0; c < HID; ++c) {
        float v = fmaf(nc, hbuf[i][c],
                  fmaf(nl, hbuf[il][c],
                  fmaf(nr, hbuf[ir][c], b1[c])));
        r1[c] = fmaxf(v, 0.0f);
    }
    __syncthreads();  // all layer-1 reads done before overwrite

    // ---- layer 2 matmul: acc = r1 @ W2 (32x32) ----
    // W2 addresses are wave-uniform -> broadcast dwordx4 (or s_load if scalarized)
    float acc[HID];
    #pragma unroll
    for (int c = 0; c < HID; ++c) acc[c] = 0.0f;
    const float4* W24 = reinterpret_cast<const float4*>(W2);
    #pragma unroll 4
    for (int k = 0; k < HID; ++k) {
        const float rk = r1[k];
        #pragma unroll
        for (int c4 = 0; c4 < HID / 4; ++c4) {
            const float4 w = W24[k * (HID / 4) + c4];
            acc[4 * c4 + 0] = fmaf(rk, w.x, acc[4 * c4 + 0]);
            acc[4 * c4 + 1] = fmaf(rk, w.y, acc[4 * c4 + 1]);
            acc[4 * c4 + 2] = fmaf(rk, w.z, acc[4 * c4 + 2]);
            acc[4 * c4 + 3] = fmaf(rk, w.w, acc[4 * c4 + 3]);
        }
    }
    #pragma unroll
    for (int c = 0; c < HID; ++c) hbuf[i][c] = acc[c];
    __syncthreads();

    // ---- stencil 2 + bias + relu -> h2 ----
    float h2[HID];
    #pragma unroll
    for (int c = 0; c < HID; ++c) {
        float v = fmaf(nc, hbuf[i][c],
                  fmaf(nl, hbuf[il][c],
                  fmaf(nr, hbuf[ir][c], b2[c])));
        h2[c] = fmaxf(v, 0.0f);
    }
    __syncthreads();  // all stencil-2 reads done before overwrite
    #pragma unroll
    for (int c = 0; c < HID; ++c) hbuf[i][c] = h2[c];
    __syncthreads();

    // ---- mean pool over 256 nodes ----
    {
        const int c = i & (HID - 1);   // channel
        const int g = i >> 5;          // node group (8 groups x 32 nodes)
        float s = 0.0f;
        #pragma unroll
        for (int j = 0; j < CL / 8; ++j)
            s += hbuf[g * (CL / 8) + j][c];
        partial[g][c] = s;
    }
    __syncthreads();
    if (i < HID) {
        float p = 0.0f;
        #pragma unroll
        for (int g = 0; g < 8; ++g) p += partial[g][i];
        pooled[i] = p * (1.0f / 256.0f);
    }
    __syncthreads();

    // ---- head phase A: body_emb (no relu!) and aux layer-1 ----
    if (i < HID) {
        float be = br[i];
        #pragma unroll 8
        for (int k = 0; k < HID; ++k)
            be = fmaf(pooled[k], Wr[k * HID + i], be);
        catbuf[i] = be;

        const float a0 = heads[2 * b];
        const float a1 = heads[2 * b + 1];
        const float a2 = body_sizes[b];
        const float a3 = fruits[2 * b];
        const float a4 = fruits[2 * b + 1];
        float a = ba1[i];
        a = fmaf(a0, Wa1[0 * HID + i], a);
        a = fmaf(a1, Wa1[1 * HID + i], a);
        a = fmaf(a2, Wa1[2 * HID + i], a);
        a = fmaf(a3, Wa1[3 * HID + i], a);
        a = fmaf(a4, Wa1[4 * HID + i], a);
        partial[0][i] = fmaxf(a, 0.0f);   // aux1
    }
    __syncthreads();

    // ---- head phase B: aux layer-2 ----
    if (i < HID) {
        float a = ba2[i];
        #pragma unroll 8
        for (int k = 0; k < HID; ++k)
            a = fmaf(partial[0][k], Wa2[k * HID + i], a);
        catbuf[HID + i] = fmaxf(a, 0.0f);
    }
    __syncthreads();

    // ---- head phase C: combined = relu(cat @ Wc + bc), 64 wide ----
    if (i < FIN) {
        float cb = bc[i];
        #pragma unroll 8
        for (int k = 0; k < FIN; ++k)
            cb = fmaf(catbuf[k], Wc[k * FIN + i], cb);
        cmb[i] = fmaxf(cb, 0.0f);
    }
    __syncthreads();

    // ---- head phase D: logits (5) + value (1) ----
    if (i < 5) {
        float lg = bp[i];
        #pragma unroll 8
        for (int k = 0; k < FIN; ++k)
            lg = fmaf(cmb[k], Wp[k * 5 + i], lg);
        out[b * 5 + i] = lg;
    } else if (i == 5) {
        float vv = bv[0];
        #pragma unroll 8
        for (int k = 0; k < FIN; ++k)
            vv = fmaf(cmb[k], Wv[k], vv);
        out[NB * 5 + b] = vv;
    }
}

extern "C" void kernel_launch(void* const* d_in, const int* in_sizes, int n_in,
                              void* d_out, int out_size, void* d_ws, size_t ws_size,
                              hipStream_t stream) {
    const float* x          = (const float*)d_in[0];
    const float* heads      = (const float*)d_in[1];
    const float* body_sizes = (const float*)d_in[2];
    const float* fruits     = (const float*)d_in[3];
    const float* W1 = (const float*)d_in[4];
    const float* b1 = (const float*)d_in[5];
    const float* W2 = (const float*)d_in[6];
    const float* b2 = (const float*)d_in[7];
    const float* Wr = (const float*)d_in[8];
    const float* br = (const float*)d_in[9];
    const float* Wa1 = (const float*)d_in[10];
    const float* ba1 = (const float*)d_in[11];
    const float* Wa2 = (const float*)d_in[12];
    const float* ba2 = (const float*)d_in[13];
    const float* Wc = (const float*)d_in[14];
    const float* bc = (const float*)d_in[15];
    const float* Wp = (const float*)d_in[16];
    const float* bp = (const float*)d_in[17];
    const float* Wv = (const float*)d_in[18];
    const float* bv = (const float*)d_in[19];
    // d_in[20] = edge_index, d_in[21] = batch_ids: chain structure is implicit.

    float* out = (float*)d_out;
    snake_fused<<<NB, CL, 0, stream>>>(
        x, heads, body_sizes, fruits,
        W1, b1, W2, b2, Wr, br, Wa1, ba1, Wa2, ba2,
        Wc, bc, Wp, bp, Wv, bv, out);
}